// Round 24
// baseline (41.762 us; speedup 1.0000x reference)
//
#include <hip/hip_runtime.h>
#include <hip/hip_bf16.h>
#include <cstdint>

#define NPIX (16 * 256 * 256)
#define THRV 0.1f

typedef __bf16 bf16x8 __attribute__((ext_vector_type(8)));
typedef float  f32x4  __attribute__((ext_vector_type(4)));

// Barrier without __syncthreads' vmcnt(0) drain: only LDS ops must be
// cross-wave visible -> lgkmcnt(0) suffices; global loads stay in flight.
#define LDS_BARRIER() do {                                    \
    asm volatile("s_waitcnt lgkmcnt(0)" ::: "memory");        \
    __builtin_amdgcn_s_barrier();                             \
} while (0)

// wpack slots (slot*64 + lane, float4 each):
//  0..3 w1f[n]   4..11 w2f[s*4+n]   12..13 w3f[s]   14..17 b2v[n]
#define NSLOT 18

// ---------------------------------------------------------------------------
// k_pack: one wave builds per-lane weight fragments (runs once, ~µs).
// psi(s,g,j) = (2s+(j>>2))*16 + g*4 + (j&3): layer N's C regs ARE layer N+1's
// B-frag -> zero-shuffle in-register MLP. w1 sobel rows pre-summed with the
// 0.125 scale folded; b1 rides k-slot (g==1,j==4) against activation 1.0.
// ---------------------------------------------------------------------------
__global__ __launch_bounds__(64) void k_pack(const float* __restrict__ w1,
                                             const float* __restrict__ b1,
                                             const float* __restrict__ w2,
                                             const float* __restrict__ b2,
                                             const float* __restrict__ w3,
                                             float4* __restrict__ wpack) {
    const int lane = threadIdx.x;
    const int r = lane & 15, g = lane >> 4;
#pragma unroll
    for (int n = 0; n < 4; ++n) {
        const int cc = n * 16 + r;
        bf16x8 f;
#pragma unroll
        for (int j = 0; j < 8; ++j) {
            float v = 0.f;
            if (j < 4) v = w1[(g * 4 + j) * 64 + cc];
            else if (g == 0 && j == 4) { for (int t = 0; t < 16; ++t) v += w1[(16 + t) * 64 + cc]; v *= 0.125f; }
            else if (g == 0 && j == 5) { for (int t = 0; t < 16; ++t) v += w1[(32 + t) * 64 + cc]; v *= 0.125f; }
            else if (g == 1 && j == 4) v = b1[cc];
            f[j] = (__bf16)v;
        }
        wpack[n * 64 + lane] = *(const float4*)&f;
    }
#pragma unroll
    for (int s = 0; s < 2; ++s)
#pragma unroll
        for (int n = 0; n < 4; ++n) {
            bf16x8 f;
#pragma unroll
            for (int j = 0; j < 8; ++j) {
                const int psi = (2 * s + (j >> 2)) * 16 + g * 4 + (j & 3);
                f[j] = (__bf16)w2[psi * 64 + n * 16 + r];
            }
            wpack[(4 + s * 4 + n) * 64 + lane] = *(const float4*)&f;
        }
#pragma unroll
    for (int s = 0; s < 2; ++s) {
        bf16x8 f;
#pragma unroll
        for (int j = 0; j < 8; ++j) {
            const int psi = (2 * s + (j >> 2)) * 16 + g * 4 + (j & 3);
            f[j] = (__bf16)w3[psi * 16 + r];
        }
        wpack[(12 + s) * 64 + lane] = *(const float4*)&f;
    }
#pragma unroll
    for (int n = 0; n < 4; ++n) {
        f32x4 v;
#pragma unroll
        for (int q = 0; q < 4; ++q) v[q] = b2[n * 16 + g * 4 + q];
        wpack[(14 + n) * 64 + lane] = *(const float4*)&v;
    }
}

// ---------------------------------------------------------------------------
// k_fused: block = 8-row band (512 blocks), rolling-row pipeline with
// PREFETCH DEPTH 3: loads issued at iteration p are consumed at p+3 —
// ~1050-1200 cyc of compute cover >= the ~900-1000 cyc loaded HBM miss
// (x is L3-COLD each replay: the harness's 268 MB inter-replay reset evicts
// the 256 MB L3; depth 1->2 already gave 42.3->40.8). Five register stages
// xf/xfA/xfN/xfNN/xfNNN. Ring-4 LDS, LDS_BARRIER, once-per-row sobel.
// ---------------------------------------------------------------------------
__global__ __launch_bounds__(256, 2) void k_fused(const float* __restrict__ x,
                                                  const float4* __restrict__ wpack,
                                                  float* __restrict__ out,
                                                  unsigned char* __restrict__ rpre,
                                                  unsigned char* __restrict__ anewf) {
    __shared__ float sS[4][256];    // ring: s of rows (y&3)
    __shared__ float sC3[4][256];   // ring: ch3 of rows (y&3)

    const int tid = threadIdx.x;
    const int wv = tid >> 6, lane = tid & 63;
    const int r = lane & 15, g = lane >> 4;

    // ---- weight fragments (coalesced, issued first) ----
    bf16x8 w1f[4], w2f[2][4], w3f[2];
    f32x4 b2v[4];
#pragma unroll
    for (int n = 0; n < 4; ++n) { float4 t = wpack[n * 64 + lane]; w1f[n] = *(bf16x8*)&t; }
#pragma unroll
    for (int s2i = 0; s2i < 2; ++s2i)
#pragma unroll
        for (int n = 0; n < 4; ++n) { float4 t = wpack[(4 + s2i * 4 + n) * 64 + lane]; w2f[s2i][n] = *(bf16x8*)&t; }
#pragma unroll
    for (int s2i = 0; s2i < 2; ++s2i) { float4 t = wpack[(12 + s2i) * 64 + lane]; w3f[s2i] = *(bf16x8*)&t; }
#pragma unroll
    for (int n = 0; n < 4; ++n) { float4 t = wpack[(14 + n) * 64 + lane]; b2v[n] = *(f32x4*)&t; }

    const int swz = (blockIdx.x & 7) * 64 + (blockIdx.x >> 3);  // bijective, 512 blocks
    const int img = swz >> 5;          // 16 images
    const int y0 = (swz & 31) * 8;     // band start row (local)
    const size_t ibase = (size_t)img << 16;
    const int wcol = wv * 64;          // wave owns 64 consecutive px of each row
    const int wc = wcol + lane;        // this lane's sobel column
    const bool scl = (wc > 0), scr = (wc < 255);

    float4 xf[4], xfA[4], xfN[4], xfNN[4], xfNNN[4];

    auto loadrow = [&](int yl, float4 dst[4]) {   // wave-layout row load; zeros if OOB
        if ((unsigned)yl < 256u) {
            const size_t rb = ibase + (size_t)yl * 256;
#pragma unroll
            for (int t = 0; t < 4; ++t)
                dst[t] = *(const float4*)(x + (rb + wcol + t * 16 + r) * 16 + g * 4);
        } else {
#pragma unroll
            for (int t = 0; t < 4; ++t) dst[t] = make_float4(0.f, 0.f, 0.f, 0.f);
        }
    };
    auto redwrite = [&](int yl, const float4 src[4]) {  // s + ch3 -> ring slot yl&3
        const int sl = yl & 3;
#pragma unroll
        for (int t = 0; t < 4; ++t) {
            float p = (src[t].x + src[t].y) + (src[t].z + src[t].w);
            p += __shfl_xor(p, 16);
            p += __shfl_xor(p, 32);
            if (g == 0) { sS[sl][wcol + t * 16 + r] = p; sC3[sl][wcol + t * 16 + r] = src[t].w; }
        }
    };

    // ---- prologue: rows y0-1 (halo), y0..y0+3 preloaded ----
    loadrow(y0 - 1, xfNNN);        // temp use; zeros if band 0
    loadrow(y0, xf);
    loadrow(y0 + 1, xfA);
    redwrite(y0 - 1, xfNNN);
    loadrow(y0 + 2, xfN);
    loadrow(y0 + 3, xfNN);
    redwrite(y0, xf);

#pragma unroll 2
    for (int p = 0; p < 8; ++p) {
        const int y = y0 + p;

        // a) issue row y+4 (consumed 3 iterations later — deep prefetch)
        const int yn = (p < 5) ? (y + 4) : 999;
        loadrow(yn, xfNNN);

        // b) s/ch3 of row y+1 from regs loaded THREE iterations ago
        redwrite(y + 1, xfA);
        LDS_BARRIER();

        const float* s0 = sS[(y - 1) & 3];
        const float* s1 = sS[y & 3];
        const float* s2 = sS[(y + 1) & 3];
        const float* c3 = sC3[y & 3];
        const size_t rb = ibase + (size_t)y * 256;

        // c) per-lane sobel + prelife for the wave's 64 columns (ONCE per row)
        float gxA, gyA;
        {
            const float r0m = scl ? s0[wc - 1] : 0.f;
            const float r0c = s0[wc];
            const float r0p = scr ? s0[wc + 1] : 0.f;
            const float r1m = scl ? s1[wc - 1] : 0.f;
            const float r1p = scr ? s1[wc + 1] : 0.f;
            const float r2m = scl ? s2[wc - 1] : 0.f;
            const float r2c = s2[wc];
            const float r2p = scr ? s2[wc + 1] : 0.f;
            // 0.125 folded into w1 at pack time
            gxA = (r0p - r0m) + 2.f * (r1p - r1m) + (r2p - r2m);
            gyA = (r2m + 2.f * r2c + r2p) - (r0m + 2.f * r0c + r0p);
            const float c3m = scl ? c3[wc - 1] : 0.f;
            const float c3c = c3[wc];
            const float c3p = scr ? c3[wc + 1] : 0.f;
            rpre[rb + wc] = (fmaxf(c3m, fmaxf(c3c, c3p)) > THRV) ? 1 : 0;  // coalesced 64B
        }

        // d) 4 tile chains
#pragma unroll
        for (int t = 0; t < 4; ++t) {
            const int col = wcol + t * 16 + r;
            const size_t pix = rb + col;
            const float gx = __shfl(gxA, t * 16 + r);   // broadcast to all g-groups
            const float gy = __shfl(gyA, t * 16 + r);

            bf16x8 a1;
            a1[0] = (__bf16)xf[t].x; a1[1] = (__bf16)xf[t].y;
            a1[2] = (__bf16)xf[t].z; a1[3] = (__bf16)xf[t].w;
            a1[4] = (__bf16)(g == 0 ? gx : (g == 1 ? 1.f : 0.f));
            a1[5] = (__bf16)(g == 0 ? gy : 0.f);
            a1[6] = (__bf16)0.f; a1[7] = (__bf16)0.f;

            f32x4 acc1[4];
#pragma unroll
            for (int n = 0; n < 4; ++n)
                acc1[n] = __builtin_amdgcn_mfma_f32_16x16x32_bf16(
                    w1f[n], a1, (f32x4){0.f, 0.f, 0.f, 0.f}, 0, 0, 0);

            bf16x8 bf2[2];
#pragma unroll
            for (int s2i = 0; s2i < 2; ++s2i)
#pragma unroll
                for (int j = 0; j < 4; ++j) {
                    bf2[s2i][j]     = (__bf16)fmaxf(acc1[2 * s2i][j], 0.f);
                    bf2[s2i][4 + j] = (__bf16)fmaxf(acc1[2 * s2i + 1][j], 0.f);
                }

            f32x4 acc2[4];
#pragma unroll
            for (int n = 0; n < 4; ++n) {
                acc2[n] = __builtin_amdgcn_mfma_f32_16x16x32_bf16(w2f[0][n], bf2[0], b2v[n], 0, 0, 0);
                acc2[n] = __builtin_amdgcn_mfma_f32_16x16x32_bf16(w2f[1][n], bf2[1], acc2[n], 0, 0, 0);
            }

            bf16x8 bf3[2];
#pragma unroll
            for (int s2i = 0; s2i < 2; ++s2i)
#pragma unroll
                for (int j = 0; j < 4; ++j) {
                    bf3[s2i][j]     = (__bf16)fmaxf(acc2[2 * s2i][j], 0.f);
                    bf3[s2i][4 + j] = (__bf16)fmaxf(acc2[2 * s2i + 1][j], 0.f);
                }

            f32x4 acc3 = __builtin_amdgcn_mfma_f32_16x16x32_bf16(
                w3f[0], bf3[0], (f32x4){0.f, 0.f, 0.f, 0.f}, 0, 0, 0);
            acc3 = __builtin_amdgcn_mfma_f32_16x16x32_bf16(w3f[1], bf3[1], acc3, 0, 0, 0);

            f32x4 xn;
            xn[0] = xf[t].x + acc3[0]; xn[1] = xf[t].y + acc3[1];
            xn[2] = xf[t].z + acc3[2]; xn[3] = xf[t].w + acc3[3];
            __builtin_nontemporal_store(xn, (f32x4*)(out + pix * 16 + g * 4));
            if (g == 0) anewf[pix] = (xn[3] > THRV) ? 1 : 0;
        }

        // e) rotate the 5-stage register pipeline (renamed away by unroll 2)
#pragma unroll
        for (int t = 0; t < 4; ++t) {
            xf[t] = xfA[t]; xfA[t] = xfN[t]; xfN[t] = xfNN[t]; xfNN[t] = xfNNN[t];
        }
    }
}

// ---------------------------------------------------------------------------
// k_post: thread = 4 pixels; bit-parallel life from byte flags.
// pre = vertical OR of rpre (already row-maxed); post = 3x3 OR of anewf.
// ---------------------------------------------------------------------------
__global__ __launch_bounds__(256) void k_post(const unsigned char* __restrict__ rpre,
                                              const unsigned char* __restrict__ anewf,
                                              float* __restrict__ out) {
    const int q = blockIdx.x * 256 + threadIdx.x;
    const int p0 = q * 4;
    const int bi = p0 >> 16;
    const int rem = p0 & 65535;
    const int y = rem >> 8;
    const int c0 = rem & 255;
    const unsigned char* pr = rpre + ((size_t)bi << 16);
    const unsigned char* an = anewf + ((size_t)bi << 16);

    unsigned pre = 0, M = 0, l = 0, rr = 0;
#pragma unroll
    for (int dy = -1; dy <= 1; ++dy) {
        const int y2 = y + dy;
        if ((unsigned)y2 >= 256u) continue;
        const int ro = y2 * 256;
        pre |= *(const unsigned*)(pr + ro + c0);
        M   |= *(const unsigned*)(an + ro + c0);
        l   |= (c0 > 0)   ? (unsigned)an[ro + c0 - 1] : 0u;
        rr  |= (c0 < 252) ? (unsigned)an[ro + c0 + 4] : 0u;
    }
    const unsigned post = M | (M << 8) | l | (M >> 8) | (rr << 24);
    const unsigned alive = pre & post;
    if (alive != 0x01010101u) {
        const f32x4 z = (f32x4){0.f, 0.f, 0.f, 0.f};
#pragma unroll
        for (int i = 0; i < 4; ++i)
            if (!((alive >> (8 * i)) & 1u)) {
                f32x4* op = (f32x4*)(out + (size_t)(p0 + i) * 16);
                op[0] = z; op[1] = z; op[2] = z; op[3] = z;
            }
    }
}

// ---------------------------------------------------------------------------
extern "C" void kernel_launch(void* const* d_in, const int* in_sizes, int n_in,
                              void* d_out, int out_size, void* d_ws, size_t ws_size,
                              hipStream_t stream) {
    const float* x  = (const float*)d_in[0];
    const float* w1 = (const float*)d_in[1];
    const float* b1 = (const float*)d_in[2];
    const float* w2 = (const float*)d_in[3];
    const float* b2 = (const float*)d_in[4];
    const float* w3 = (const float*)d_in[5];
    float* out = (float*)d_out;

    unsigned char* rpre  = (unsigned char*)d_ws;     // NPIX bytes
    unsigned char* anewf = rpre + NPIX;              // NPIX bytes
    float4* wpack = (float4*)(anewf + NPIX);         // NSLOT*64 float4

    hipLaunchKernelGGL(k_pack, dim3(1), dim3(64), 0, stream, w1, b1, w2, b2, w3, wpack);
    hipLaunchKernelGGL(k_fused, dim3(512), dim3(256), 0, stream,
                       x, wpack, out, rpre, anewf);
    hipLaunchKernelGGL(k_post, dim3(NPIX / 1024), dim3(256), 0, stream,
                       rpre, anewf, out);
}

// Round 25
// 40.809 us; speedup vs baseline: 1.0234x; 1.0234x over previous
//
#include <hip/hip_runtime.h>
#include <hip/hip_bf16.h>
#include <cstdint>

#define NPIX (16 * 256 * 256)
#define THRV 0.1f

typedef __bf16 bf16x8 __attribute__((ext_vector_type(8)));
typedef float  f32x4  __attribute__((ext_vector_type(4)));

// Barrier without __syncthreads' vmcnt(0) drain: only LDS ops must be
// cross-wave visible -> lgkmcnt(0) suffices; global loads stay in flight.
#define LDS_BARRIER() do {                                    \
    asm volatile("s_waitcnt lgkmcnt(0)" ::: "memory");        \
    __builtin_amdgcn_s_barrier();                             \
} while (0)

// wpack slots (slot*64 + lane, float4 each):
//  0..3 w1f[n]   4..11 w2f[s*4+n]   12..13 w3f[s]   14..17 b2v[n]
#define NSLOT 18

// ---------------------------------------------------------------------------
// k_pack: one wave builds per-lane weight fragments (runs once, ~µs).
// psi(s,g,j) = (2s+(j>>2))*16 + g*4 + (j&3): layer N's C regs ARE layer N+1's
// B-frag -> zero-shuffle in-register MLP. w1 sobel rows pre-summed with the
// 0.125 scale folded; b1 rides k-slot (g==1,j==4) against activation 1.0.
// ---------------------------------------------------------------------------
__global__ __launch_bounds__(64) void k_pack(const float* __restrict__ w1,
                                             const float* __restrict__ b1,
                                             const float* __restrict__ w2,
                                             const float* __restrict__ b2,
                                             const float* __restrict__ w3,
                                             float4* __restrict__ wpack) {
    const int lane = threadIdx.x;
    const int r = lane & 15, g = lane >> 4;
#pragma unroll
    for (int n = 0; n < 4; ++n) {
        const int cc = n * 16 + r;
        bf16x8 f;
#pragma unroll
        for (int j = 0; j < 8; ++j) {
            float v = 0.f;
            if (j < 4) v = w1[(g * 4 + j) * 64 + cc];
            else if (g == 0 && j == 4) { for (int t = 0; t < 16; ++t) v += w1[(16 + t) * 64 + cc]; v *= 0.125f; }
            else if (g == 0 && j == 5) { for (int t = 0; t < 16; ++t) v += w1[(32 + t) * 64 + cc]; v *= 0.125f; }
            else if (g == 1 && j == 4) v = b1[cc];
            f[j] = (__bf16)v;
        }
        wpack[n * 64 + lane] = *(const float4*)&f;
    }
#pragma unroll
    for (int s = 0; s < 2; ++s)
#pragma unroll
        for (int n = 0; n < 4; ++n) {
            bf16x8 f;
#pragma unroll
            for (int j = 0; j < 8; ++j) {
                const int psi = (2 * s + (j >> 2)) * 16 + g * 4 + (j & 3);
                f[j] = (__bf16)w2[psi * 64 + n * 16 + r];
            }
            wpack[(4 + s * 4 + n) * 64 + lane] = *(const float4*)&f;
        }
#pragma unroll
    for (int s = 0; s < 2; ++s) {
        bf16x8 f;
#pragma unroll
        for (int j = 0; j < 8; ++j) {
            const int psi = (2 * s + (j >> 2)) * 16 + g * 4 + (j & 3);
            f[j] = (__bf16)w3[psi * 16 + r];
        }
        wpack[(12 + s) * 64 + lane] = *(const float4*)&f;
    }
#pragma unroll
    for (int n = 0; n < 4; ++n) {
        f32x4 v;
#pragma unroll
        for (int q = 0; q < 4; ++q) v[q] = b2[n * 16 + g * 4 + q];
        wpack[(14 + n) * 64 + lane] = *(const float4*)&v;
    }
}

// ---------------------------------------------------------------------------
// k_fused: block = 8-row band (512 blocks), rolling-row pipeline with
// PREFETCH DEPTH 2 (the measured optimum: depth 1 = 42.3 us, 2 = 40.8,
// 3 = 41.8): loads issued at iteration p are consumed at p+2 — ~700-800 cyc
// of compute cover against the ~900-1000 cyc loaded HBM miss (x is L3-COLD
// each replay: the harness's 268 MB inter-replay reset evicts the 256 MB L3;
// FETCH=41 MB/replay confirms). Ring-4 LDS, LDS_BARRIER, once-per-row
// sobel+prelife (lane-per-column), unroll-2 register rotation.
// ---------------------------------------------------------------------------
__global__ __launch_bounds__(256, 2) void k_fused(const float* __restrict__ x,
                                                  const float4* __restrict__ wpack,
                                                  float* __restrict__ out,
                                                  unsigned char* __restrict__ rpre,
                                                  unsigned char* __restrict__ anewf) {
    __shared__ float sS[4][256];    // ring: s of rows (y&3)
    __shared__ float sC3[4][256];   // ring: ch3 of rows (y&3)

    const int tid = threadIdx.x;
    const int wv = tid >> 6, lane = tid & 63;
    const int r = lane & 15, g = lane >> 4;

    // ---- weight fragments (coalesced, issued first) ----
    bf16x8 w1f[4], w2f[2][4], w3f[2];
    f32x4 b2v[4];
#pragma unroll
    for (int n = 0; n < 4; ++n) { float4 t = wpack[n * 64 + lane]; w1f[n] = *(bf16x8*)&t; }
#pragma unroll
    for (int s2i = 0; s2i < 2; ++s2i)
#pragma unroll
        for (int n = 0; n < 4; ++n) { float4 t = wpack[(4 + s2i * 4 + n) * 64 + lane]; w2f[s2i][n] = *(bf16x8*)&t; }
#pragma unroll
    for (int s2i = 0; s2i < 2; ++s2i) { float4 t = wpack[(12 + s2i) * 64 + lane]; w3f[s2i] = *(bf16x8*)&t; }
#pragma unroll
    for (int n = 0; n < 4; ++n) { float4 t = wpack[(14 + n) * 64 + lane]; b2v[n] = *(f32x4*)&t; }

    const int swz = (blockIdx.x & 7) * 64 + (blockIdx.x >> 3);  // bijective, 512 blocks
    const int img = swz >> 5;          // 16 images
    const int y0 = (swz & 31) * 8;     // band start row (local)
    const size_t ibase = (size_t)img << 16;
    const int wcol = wv * 64;          // wave owns 64 consecutive px of each row
    const int wc = wcol + lane;        // this lane's sobel column
    const bool scl = (wc > 0), scr = (wc < 255);

    float4 xf[4], xfA[4], xfN[4], xfNN[4];

    auto loadrow = [&](int yl, float4 dst[4]) {   // wave-layout row load; zeros if OOB
        if ((unsigned)yl < 256u) {
            const size_t rb = ibase + (size_t)yl * 256;
#pragma unroll
            for (int t = 0; t < 4; ++t)
                dst[t] = *(const float4*)(x + (rb + wcol + t * 16 + r) * 16 + g * 4);
        } else {
#pragma unroll
            for (int t = 0; t < 4; ++t) dst[t] = make_float4(0.f, 0.f, 0.f, 0.f);
        }
    };
    auto redwrite = [&](int yl, const float4 src[4]) {  // s + ch3 -> ring slot yl&3
        const int sl = yl & 3;
#pragma unroll
        for (int t = 0; t < 4; ++t) {
            float p = (src[t].x + src[t].y) + (src[t].z + src[t].w);
            p += __shfl_xor(p, 16);
            p += __shfl_xor(p, 32);
            if (g == 0) { sS[sl][wcol + t * 16 + r] = p; sC3[sl][wcol + t * 16 + r] = src[t].w; }
        }
    };

    // ---- prologue: rows y0-1 (halo), y0, y0+1, y0+2 ----
    loadrow(y0 - 1, xfNN);         // temp use; zeros if band 0
    loadrow(y0, xf);
    loadrow(y0 + 1, xfA);
    redwrite(y0 - 1, xfNN);
    loadrow(y0 + 2, xfN);
    redwrite(y0, xf);

#pragma unroll 2
    for (int p = 0; p < 8; ++p) {
        const int y = y0 + p;

        // a) issue row y+3 (consumed 2 iterations later — deep prefetch)
        const int yn = (p < 6) ? (y + 3) : 999;
        loadrow(yn, xfNN);

        // b) s/ch3 of row y+1 from regs loaded TWO iterations ago
        redwrite(y + 1, xfA);
        LDS_BARRIER();

        const float* s0 = sS[(y - 1) & 3];
        const float* s1 = sS[y & 3];
        const float* s2 = sS[(y + 1) & 3];
        const float* c3 = sC3[y & 3];
        const size_t rb = ibase + (size_t)y * 256;

        // c) per-lane sobel + prelife for the wave's 64 columns (ONCE per row)
        float gxA, gyA;
        {
            const float r0m = scl ? s0[wc - 1] : 0.f;
            const float r0c = s0[wc];
            const float r0p = scr ? s0[wc + 1] : 0.f;
            const float r1m = scl ? s1[wc - 1] : 0.f;
            const float r1p = scr ? s1[wc + 1] : 0.f;
            const float r2m = scl ? s2[wc - 1] : 0.f;
            const float r2c = s2[wc];
            const float r2p = scr ? s2[wc + 1] : 0.f;
            // 0.125 folded into w1 at pack time
            gxA = (r0p - r0m) + 2.f * (r1p - r1m) + (r2p - r2m);
            gyA = (r2m + 2.f * r2c + r2p) - (r0m + 2.f * r0c + r0p);
            const float c3m = scl ? c3[wc - 1] : 0.f;
            const float c3c = c3[wc];
            const float c3p = scr ? c3[wc + 1] : 0.f;
            rpre[rb + wc] = (fmaxf(c3m, fmaxf(c3c, c3p)) > THRV) ? 1 : 0;  // coalesced 64B
        }

        // d) 4 tile chains
#pragma unroll
        for (int t = 0; t < 4; ++t) {
            const int col = wcol + t * 16 + r;
            const size_t pix = rb + col;
            const float gx = __shfl(gxA, t * 16 + r);   // broadcast to all g-groups
            const float gy = __shfl(gyA, t * 16 + r);

            bf16x8 a1;
            a1[0] = (__bf16)xf[t].x; a1[1] = (__bf16)xf[t].y;
            a1[2] = (__bf16)xf[t].z; a1[3] = (__bf16)xf[t].w;
            a1[4] = (__bf16)(g == 0 ? gx : (g == 1 ? 1.f : 0.f));
            a1[5] = (__bf16)(g == 0 ? gy : 0.f);
            a1[6] = (__bf16)0.f; a1[7] = (__bf16)0.f;

            f32x4 acc1[4];
#pragma unroll
            for (int n = 0; n < 4; ++n)
                acc1[n] = __builtin_amdgcn_mfma_f32_16x16x32_bf16(
                    w1f[n], a1, (f32x4){0.f, 0.f, 0.f, 0.f}, 0, 0, 0);

            bf16x8 bf2[2];
#pragma unroll
            for (int s2i = 0; s2i < 2; ++s2i)
#pragma unroll
                for (int j = 0; j < 4; ++j) {
                    bf2[s2i][j]     = (__bf16)fmaxf(acc1[2 * s2i][j], 0.f);
                    bf2[s2i][4 + j] = (__bf16)fmaxf(acc1[2 * s2i + 1][j], 0.f);
                }

            f32x4 acc2[4];
#pragma unroll
            for (int n = 0; n < 4; ++n) {
                acc2[n] = __builtin_amdgcn_mfma_f32_16x16x32_bf16(w2f[0][n], bf2[0], b2v[n], 0, 0, 0);
                acc2[n] = __builtin_amdgcn_mfma_f32_16x16x32_bf16(w2f[1][n], bf2[1], acc2[n], 0, 0, 0);
            }

            bf16x8 bf3[2];
#pragma unroll
            for (int s2i = 0; s2i < 2; ++s2i)
#pragma unroll
                for (int j = 0; j < 4; ++j) {
                    bf3[s2i][j]     = (__bf16)fmaxf(acc2[2 * s2i][j], 0.f);
                    bf3[s2i][4 + j] = (__bf16)fmaxf(acc2[2 * s2i + 1][j], 0.f);
                }

            f32x4 acc3 = __builtin_amdgcn_mfma_f32_16x16x32_bf16(
                w3f[0], bf3[0], (f32x4){0.f, 0.f, 0.f, 0.f}, 0, 0, 0);
            acc3 = __builtin_amdgcn_mfma_f32_16x16x32_bf16(w3f[1], bf3[1], acc3, 0, 0, 0);

            f32x4 xn;
            xn[0] = xf[t].x + acc3[0]; xn[1] = xf[t].y + acc3[1];
            xn[2] = xf[t].z + acc3[2]; xn[3] = xf[t].w + acc3[3];
            __builtin_nontemporal_store(xn, (f32x4*)(out + pix * 16 + g * 4));
            if (g == 0) anewf[pix] = (xn[3] > THRV) ? 1 : 0;
        }

        // e) rotate the 4-stage register pipeline (renamed away by unroll 2)
#pragma unroll
        for (int t = 0; t < 4; ++t) { xf[t] = xfA[t]; xfA[t] = xfN[t]; xfN[t] = xfNN[t]; }
    }
}

// ---------------------------------------------------------------------------
// k_post: thread = 4 pixels; bit-parallel life from byte flags.
// pre = vertical OR of rpre (already row-maxed); post = 3x3 OR of anewf.
// ---------------------------------------------------------------------------
__global__ __launch_bounds__(256) void k_post(const unsigned char* __restrict__ rpre,
                                              const unsigned char* __restrict__ anewf,
                                              float* __restrict__ out) {
    const int q = blockIdx.x * 256 + threadIdx.x;
    const int p0 = q * 4;
    const int bi = p0 >> 16;
    const int rem = p0 & 65535;
    const int y = rem >> 8;
    const int c0 = rem & 255;
    const unsigned char* pr = rpre + ((size_t)bi << 16);
    const unsigned char* an = anewf + ((size_t)bi << 16);

    unsigned pre = 0, M = 0, l = 0, rr = 0;
#pragma unroll
    for (int dy = -1; dy <= 1; ++dy) {
        const int y2 = y + dy;
        if ((unsigned)y2 >= 256u) continue;
        const int ro = y2 * 256;
        pre |= *(const unsigned*)(pr + ro + c0);
        M   |= *(const unsigned*)(an + ro + c0);
        l   |= (c0 > 0)   ? (unsigned)an[ro + c0 - 1] : 0u;
        rr  |= (c0 < 252) ? (unsigned)an[ro + c0 + 4] : 0u;
    }
    const unsigned post = M | (M << 8) | l | (M >> 8) | (rr << 24);
    const unsigned alive = pre & post;
    if (alive != 0x01010101u) {
        const f32x4 z = (f32x4){0.f, 0.f, 0.f, 0.f};
#pragma unroll
        for (int i = 0; i < 4; ++i)
            if (!((alive >> (8 * i)) & 1u)) {
                f32x4* op = (f32x4*)(out + (size_t)(p0 + i) * 16);
                op[0] = z; op[1] = z; op[2] = z; op[3] = z;
            }
    }
}

// ---------------------------------------------------------------------------
extern "C" void kernel_launch(void* const* d_in, const int* in_sizes, int n_in,
                              void* d_out, int out_size, void* d_ws, size_t ws_size,
                              hipStream_t stream) {
    const float* x  = (const float*)d_in[0];
    const float* w1 = (const float*)d_in[1];
    const float* b1 = (const float*)d_in[2];
    const float* w2 = (const float*)d_in[3];
    const float* b2 = (const float*)d_in[4];
    const float* w3 = (const float*)d_in[5];
    float* out = (float*)d_out;

    unsigned char* rpre  = (unsigned char*)d_ws;     // NPIX bytes
    unsigned char* anewf = rpre + NPIX;              // NPIX bytes
    float4* wpack = (float4*)(anewf + NPIX);         // NSLOT*64 float4

    hipLaunchKernelGGL(k_pack, dim3(1), dim3(64), 0, stream, w1, b1, w2, b2, w3, wpack);
    hipLaunchKernelGGL(k_fused, dim3(512), dim3(256), 0, stream,
                       x, wpack, out, rpre, anewf);
    hipLaunchKernelGGL(k_post, dim3(NPIX / 1024), dim3(256), 0, stream,
                       rpre, anewf, out);
}